// Round 9
// baseline (541.248 us; speedup 1.0000x reference)
//
#include <hip/hip_runtime.h>
#include <cstdint>
#include <cstddef>

// ---------------------------------------------------------------------------
// SDHGNN round 17: attn4 chunk-loop micro-opt only (rest = round 16).
//  - Branchless online-softmax update (bit-exact: exp2(0)==1): removes the
//    per-lane divergent branch executed 2x2x16x2 times per wave.
//  - Explicit next-chunk register prefetch: K in pass 1, K+V in pass 2
//    (+32 VGPR, fine at 4 waves/SIMD) -> L2 latency hidden under the
//    exp/update chain of the current chunk.
// ---------------------------------------------------------------------------

#define NB 2
#define ND 128
#define NH 4
#define NN 2048
#define ND2 256
#define DN (ND*NN)
#define BDN (NB*DN)
// (1/sqrt(32)) * log2(e): scores produced directly in exp2 domain.
#define QK_SCALE 0.2550348623f
#define IN_EPS 1e-3f

typedef unsigned short u16;
typedef __attribute__((ext_vector_type(8))) short short8;
typedef __attribute__((ext_vector_type(4))) float f32x4;

__device__ __forceinline__ u16 f2bf(float f) {
    unsigned u = __float_as_uint(f);
    return (u16)((u + 0x7fffu + ((u >> 16) & 1u)) >> 16);
}
__device__ __forceinline__ float bf2f(u16 h) {
    return __uint_as_float(((unsigned)h) << 16);
}
__device__ __forceinline__ float fexp2(float x) {
#if __has_builtin(__builtin_amdgcn_exp2f)
    return __builtin_amdgcn_exp2f(x);
#else
    return exp2f(x);
#endif
}
__device__ __forceinline__ unsigned cvtpk_bf16(float a, float b) {
    unsigned r;
    asm("v_cvt_pk_bf16_f32 %0, %1, %2" : "=v"(r) : "v"(a), "v"(b));
    return r;
}

// ---------------------------------------------------------------------------
__global__ __launch_bounds__(256) void init_kernel(
    const float* __restrict__ x0in, const float* __restrict__ x1in,
    float* __restrict__ out, int* __restrict__ idx0, int* __restrict__ idx1)
{
    int tid = blockIdx.x * 256 + threadIdx.x;
    const float4* a = (const float4*)x0in;
    const float4* b = (const float4*)x1in;
    float4* o = (float4*)out;
    o[tid] = a[tid];
    o[BDN/4 + tid] = b[tid];
    if (tid < NB*NN) {
        int v = tid & (NN-1);
        idx0[tid] = v;
        idx1[tid] = v;
    }
}

// ---------------------------------------------------------------------------
// weights -> bf16 hi/lo planes with permutations:
//   Wq/Wk/Wv rows permuted o' = h*32+i; Wm cols permuted; W1 cols 0..127
//   copied, cols 128..255 FUSED = W1[:,128:]·Wm (col-permuted); W2 unchanged.
// Tail: bias permutes + b1' = b1 + W1[:,128:]·bm.
// ---------------------------------------------------------------------------
__global__ __launch_bounds__(256) void wrepack2_kernel(
    const float* __restrict__ Wq, const float* __restrict__ Wk,
    const float* __restrict__ Wv, const float* __restrict__ Wm,
    const float* __restrict__ W1, const float* __restrict__ W2,
    const float* __restrict__ bq, const float* __restrict__ bk,
    const float* __restrict__ bv, const float* __restrict__ bm,
    const float* __restrict__ b1,
    u16* __restrict__ whi, u16* __restrict__ wlo,
    float* __restrict__ bqp, float* __restrict__ bkp, float* __restrict__ bvp,
    float* __restrict__ b1p)
{
    int e = blockIdx.x * 256 + threadIdx.x;
    if (e < 655360) {
        int l = e / 163840, r = e - l*163840;
        float v;
        if (r < 49152) {
            int m = r >> 14;
            int rr = r & 16383;
            int o = rr >> 7, c = rr & 127;
            int so = (o & 31)*4 + (o >> 5);
            const float* W = (m == 0) ? Wq : ((m == 1) ? Wk : Wv);
            v = W[l*16384 + so*128 + c];
        } else if (r < 65536) {
            int rr = r - 49152;
            int o = rr >> 7, c = rr & 127;
            int sc = (c & 31)*4 + (c >> 5);
            v = Wm[l*16384 + o*128 + sc];
        } else if (r < 131072) {
            int rr = r - 65536;              // o*256 + c
            int c = rr & 255;
            if (c < 128) {
                v = W1[l*65536 + rr];
            } else {
                // fused: W1b'[o][c-128] = sum_k W1[o][128+k] * Wm[k][sc]
                int o = rr >> 8, cc = c - 128;
                int sc = (cc & 31)*4 + (cc >> 5);
                const float* w1row = &W1[l*65536 + o*256 + 128];
                const float* wmcol = &Wm[l*16384 + sc];
                float acc = 0.f;
                #pragma unroll 4
                for (int k = 0; k < 128; ++k)
                    acc = fmaf(w1row[k], wmcol[k*128], acc);
                v = acc;
            }
        }
        else                   v = W2[l*32768 + r - 131072];
        u16 hb = f2bf(v);
        whi[e] = hb;
        wlo[e] = f2bf(v - bf2f(hb));
    } else if (e < 656896) {
        int eb = e - 655360;
        int l = eb / 384, rr = eb % 384;
        int which = rr >> 7, o = rr & 127;
        int so = (o & 31)*4 + (o >> 5);
        float v = (which == 0 ? bq : (which == 1 ? bk : bv))[l*128 + so];
        (which == 0 ? bqp : (which == 1 ? bkp : bvp))[l*128 + o] = v;
    } else if (e < 657920) {
        // b1'[l][o] = b1[l][o] + sum_k W1[o][128+k] * bm[k]
        int idx = e - 656896;
        int l = idx >> 8, o = idx & 255;
        const float* w1row = &W1[l*65536 + o*256 + 128];
        const float* bmv = &bm[l*128];
        float acc = b1[l*256 + o];
        #pragma unroll 4
        for (int k = 0; k < 128; ++k)
            acc = fmaf(w1row[k], bmv[k], acc);
        b1p[l*256 + o] = acc;
    }
}

// ---------------------------------------------------------------------------
// fp32 [z][128][NN] -> bf16 hi/lo planes [z][n][128] (initial x planes)
// ---------------------------------------------------------------------------
__global__ __launch_bounds__(256) void repack_xh_kernel(
    const float* __restrict__ in, u16* __restrict__ ohi, u16* __restrict__ olo)
{
    __shared__ float tile[32][68];
    int z = blockIdx.y >> 2, cg = blockIdx.y & 3;
    int n0 = blockIdx.x * 64;
    int t = threadIdx.x;
    {
        int i = t >> 3, nc = (t & 7) * 8;
        const float* src = &in[((size_t)z*128 + cg*32 + i)*NN + n0 + nc];
        float4 a = *(const float4*)src;
        float4 b = *(const float4*)(src + 4);
        tile[i][nc+0]=a.x; tile[i][nc+1]=a.y; tile[i][nc+2]=a.z; tile[i][nc+3]=a.w;
        tile[i][nc+4]=b.x; tile[i][nc+5]=b.y; tile[i][nc+6]=b.z; tile[i][nc+7]=b.w;
    }
    __syncthreads();
    int n = t >> 2, c8 = (t & 3) * 8;
    short8 hi, lo;
    #pragma unroll
    for (int j = 0; j < 8; ++j) {
        float v = tile[c8 + j][n];
        u16 h = f2bf(v);
        hi[j] = (short)h;
        lo[j] = (short)f2bf(v - bf2f(h));
    }
    size_t ob = ((size_t)z*NN + n0 + n)*128 + cg*32 + c8;
    *(short8*)&ohi[ob] = hi;
    *(short8*)&olo[ob] = lo;
}

// ---------------------------------------------------------------------------
// shared 64x64 GEMM core, split-bf16 3-term, K-chunk 32, 4 waves 2x2 subtiles.
// T14: next K-chunk's global loads issued into registers during compute;
// only reg->LDS writes sit between barriers. (unchanged)
// ---------------------------------------------------------------------------
__device__ __forceinline__ void gcore(
    u16* As0, u16* As1, u16* Bs0, u16* Bs1,
    const u16* __restrict__ Whi, const u16* __restrict__ Wlo, int o0, int Cin,
    const u16* __restrict__ B1hi, const u16* __restrict__ B1lo, int s1,
    const u16* __restrict__ B2hi, const u16* __restrict__ B2lo, int s2, int split,
    size_t brow, int n0, const int* __restrict__ idxp, int t, f32x4 acc[2][2])
{
    const int lane = t & 63, w = t >> 6;
    const int l15 = lane & 15, quad = lane >> 4;
    const int wr = (w & 1)*32, wc = (w >> 1)*32;
    const int ao = t >> 2, ak = (t & 3)*8;
    int grow = n0 + ao;
    if (idxp) grow = idxp[grow];

    short8 rA0, rA1, rB0, rB1;
    {
        size_t wa = (size_t)(o0 + ao)*Cin + ak;
        rA0 = *(const short8*)&Whi[wa];
        rA1 = *(const short8*)&Wlo[wa];
        int c = ak;
        const u16 *ph, *pl; size_t off;
        if (c < split) { ph = B1hi; pl = B1lo; off = (brow + grow)*s1 + c; }
        else { ph = B2hi; pl = B2lo; off = (brow + grow)*s2 + (c - split); }
        rB0 = *(const short8*)&ph[off];
        rB1 = *(const short8*)&pl[off];
    }
    for (int kc = 0; kc < Cin; kc += 32) {
        __syncthreads();
        *(short8*)&As0[ao*40 + ak] = rA0;
        *(short8*)&As1[ao*40 + ak] = rA1;
        *(short8*)&Bs0[ao*40 + ak] = rB0;
        *(short8*)&Bs1[ao*40 + ak] = rB1;
        if (kc + 32 < Cin) {
            size_t wa = (size_t)(o0 + ao)*Cin + kc + 32 + ak;
            rA0 = *(const short8*)&Whi[wa];
            rA1 = *(const short8*)&Wlo[wa];
            int c = kc + 32 + ak;
            const u16 *ph, *pl; size_t off;
            if (c < split) { ph = B1hi; pl = B1lo; off = (brow + grow)*s1 + c; }
            else { ph = B2hi; pl = B2lo; off = (brow + grow)*s2 + (c - split); }
            rB0 = *(const short8*)&ph[off];
            rB1 = *(const short8*)&pl[off];
        }
        __syncthreads();
        short8 Ah[2], Al[2], Bh[2], Bl[2];
        #pragma unroll
        for (int a = 0; a < 2; ++a) {
            Ah[a] = *(const short8*)&As0[(wr + a*16 + l15)*40 + quad*8];
            Al[a] = *(const short8*)&As1[(wr + a*16 + l15)*40 + quad*8];
        }
        #pragma unroll
        for (int c = 0; c < 2; ++c) {
            Bh[c] = *(const short8*)&Bs0[(wc + c*16 + l15)*40 + quad*8];
            Bl[c] = *(const short8*)&Bs1[(wc + c*16 + l15)*40 + quad*8];
        }
        #pragma unroll
        for (int a = 0; a < 2; ++a)
            #pragma unroll
            for (int c = 0; c < 2; ++c) {
                acc[a][c] = __builtin_amdgcn_mfma_f32_16x16x32_bf16(Ah[a], Bl[c], acc[a][c], 0,0,0);
                acc[a][c] = __builtin_amdgcn_mfma_f32_16x16x32_bf16(Al[a], Bh[c], acc[a][c], 0,0,0);
                acc[a][c] = __builtin_amdgcn_mfma_f32_16x16x32_bf16(Ah[a], Bh[c], acc[a][c], 0,0,0);
            }
    }
    __syncthreads();
}

// ---------------------------------------------------------------------------
// gcore variant for w2: B comes from fp32 zf_t [z][n][256] with inline
// instnorm+relu+bf16 split (stats from LDS). A path / MFMA identical.
// ---------------------------------------------------------------------------
__device__ __forceinline__ void gcore_w2(
    u16* As0, u16* As1, u16* Bs0, u16* Bs1,
    const u16* __restrict__ Whi, const u16* __restrict__ Wlo, int o0,
    const float* __restrict__ zft, const float* __restrict__ meanL,
    const float* __restrict__ ivL,
    size_t brow, int n0, int t, f32x4 acc[2][2])
{
    const int Cin = 256;
    const int lane = t & 63, w = t >> 6;
    const int l15 = lane & 15, quad = lane >> 4;
    const int wr = (w & 1)*32, wc = (w >> 1)*32;
    const int ao = t >> 2, ak = (t & 3)*8;
    const float* brows = &zft[(brow + n0 + ao)*256];

    short8 rA0, rA1, rBh, rBl;
    {
        size_t wa = (size_t)(o0 + ao)*Cin + ak;
        rA0 = *(const short8*)&Whi[wa];
        rA1 = *(const short8*)&Wlo[wa];
        float4 f0 = *(const float4*)&brows[ak];
        float4 f1 = *(const float4*)&brows[ak + 4];
        float f[8] = {f0.x,f0.y,f0.z,f0.w,f1.x,f1.y,f1.z,f1.w};
        #pragma unroll
        for (int j = 0; j < 8; ++j) {
            float v = (f[j] - meanL[ak + j]) * ivL[ak + j];
            v = v > 0.f ? v : 0.f;
            u16 hb = f2bf(v);
            rBh[j] = (short)hb;
            rBl[j] = (short)f2bf(v - bf2f(hb));
        }
    }
    for (int kc = 0; kc < Cin; kc += 32) {
        __syncthreads();
        *(short8*)&As0[ao*40 + ak] = rA0;
        *(short8*)&As1[ao*40 + ak] = rA1;
        *(short8*)&Bs0[ao*40 + ak] = rBh;
        *(short8*)&Bs1[ao*40 + ak] = rBl;
        float4 f0n, f1n;
        const bool more = (kc + 32 < Cin);
        if (more) {
            size_t wa = (size_t)(o0 + ao)*Cin + kc + 32 + ak;
            rA0 = *(const short8*)&Whi[wa];
            rA1 = *(const short8*)&Wlo[wa];
            f0n = *(const float4*)&brows[kc + 32 + ak];
            f1n = *(const float4*)&brows[kc + 32 + ak + 4];
        }
        __syncthreads();
        short8 Ah[2], Al[2], Bh[2], Bl[2];
        #pragma unroll
        for (int a = 0; a < 2; ++a) {
            Ah[a] = *(const short8*)&As0[(wr + a*16 + l15)*40 + quad*8];
            Al[a] = *(const short8*)&As1[(wr + a*16 + l15)*40 + quad*8];
        }
        #pragma unroll
        for (int c = 0; c < 2; ++c) {
            Bh[c] = *(const short8*)&Bs0[(wc + c*16 + l15)*40 + quad*8];
            Bl[c] = *(const short8*)&Bs1[(wc + c*16 + l15)*40 + quad*8];
        }
        #pragma unroll
        for (int a = 0; a < 2; ++a)
            #pragma unroll
            for (int c = 0; c < 2; ++c) {
                acc[a][c] = __builtin_amdgcn_mfma_f32_16x16x32_bf16(Ah[a], Bl[c], acc[a][c], 0,0,0);
                acc[a][c] = __builtin_amdgcn_mfma_f32_16x16x32_bf16(Al[a], Bh[c], acc[a][c], 0,0,0);
                acc[a][c] = __builtin_amdgcn_mfma_f32_16x16x32_bf16(Ah[a], Bh[c], acc[a][c], 0,0,0);
            }
        if (more) {
            float f[8] = {f0n.x,f0n.y,f0n.z,f0n.w,f1n.x,f1n.y,f1n.z,f1n.w};
            #pragma unroll
            for (int j = 0; j < 8; ++j) {
                int cc = kc + 32 + ak + j;
                float v = (f[j] - meanL[cc]) * ivL[cc];
                v = v > 0.f ? v : 0.f;
                u16 hb = f2bf(v);
                rBh[j] = (short)hb;
                rBl[j] = (short)f2bf(v - bf2f(hb));
            }
        }
    }
    __syncthreads();
}

// ---------------------------------------------------------------------------
// Fused QKV (unchanged).
// ---------------------------------------------------------------------------
__global__ __launch_bounds__(256) void qkv_kernel(
    const u16* __restrict__ Whi, const u16* __restrict__ Wlo,
    const float* __restrict__ bqp, const float* __restrict__ bkp,
    const float* __restrict__ bvp,
    const u16* __restrict__ xphi, const u16* __restrict__ xplo,
    const int* __restrict__ idx0, const int* __restrict__ idx1,
    int cross, int M,
    u16* __restrict__ qthi, u16* __restrict__ qtlo,
    u16* __restrict__ kthi, u16* __restrict__ ktlo,
    u16* __restrict__ vthi, float* __restrict__ p,
    float* __restrict__ gsum, float* __restrict__ gsq)
{
    __shared__ u16 gsm[10240];
    u16* As0 = gsm;  u16* As1 = gsm + 2560;
    u16* Bs0 = gsm + 5120; u16* Bs1 = gsm + 7680;
    float* tb = (float*)gsm;                 // [64][66]

    const int z = blockIdx.z;
    const int bx = blockIdx.x;
    const int t = threadIdx.x;
    const int lane = t & 63, w = t >> 6;
    const int l15 = lane & 15, quad = lane >> 4;
    const int wr = (w & 1)*32, wc = (w >> 1)*32;

    int role, o0, n0, nCols;
    const u16 *Wbh, *Wbl;
    const float* bias;
    if (bx < 64) {
        role = 0; o0 = (bx & 1)*64; n0 = (bx >> 1)*64; nCols = NN;
        Wbh = Whi; Wbl = Wlo; bias = bqp;
        if (t < 32) p[(size_t)z*NN + bx*32 + t] = 0.f;
        if (bx == 0) { gsum[z*256 + t] = 0.f; gsq[z*256 + t] = 0.f; }
    } else {
        int e = bx - 64;
        int kt = M >> 6;
        int ct = e % kt, rt = e / kt;
        n0 = ct*64; nCols = M;
        if (rt < 2) { role = 1; o0 = rt*64; Wbh = Whi+16384; Wbl = Wlo+16384; bias = bkp; }
        else        { role = 2; o0 = (rt-2)*64; Wbh = Whi+32768; Wbl = Wlo+32768; bias = bvp; }
    }
    size_t brow = (size_t)z * NN;
    const int* idxp = nullptr;
    if (role != 0) {
        int ss = cross ? 1 - (z >> 1) : (z >> 1);
        brow = (size_t)(ss*2 + (z & 1)) * NN;
        idxp = (ss ? idx1 : idx0) + (z & 1)*NN;
    }

    f32x4 acc[2][2];
    #pragma unroll
    for (int a = 0; a < 2; ++a)
        #pragma unroll
        for (int c = 0; c < 2; ++c) acc[a][c] = (f32x4){0.f,0.f,0.f,0.f};

    gcore(As0, As1, Bs0, Bs1, Wbh, Wbl, o0, 128,
          xphi, xplo, 128, xphi, xplo, 128, 128, brow, n0, idxp, t, acc);

    if (role == 2) {
        #pragma unroll
        for (int a = 0; a < 2; ++a)
            #pragma unroll
            for (int c = 0; c < 2; ++c)
                #pragma unroll
                for (int r = 0; r < 4; ++r) {
                    int row = o0 + wr + a*16 + quad*4 + r;
                    int m = n0 + wc + c*16 + l15;
                    float v = acc[a][c][r] + bias[row];
                    vthi[((size_t)(z*4 + (row>>5))*32 + (row&31))*(size_t)M + m] = f2bf(v);
                }
    } else {
        float scale = role ? 1.f : QK_SCALE;
        #pragma unroll
        for (int a = 0; a < 2; ++a)
            #pragma unroll
            for (int c = 0; c < 2; ++c)
                #pragma unroll
                for (int r = 0; r < 4; ++r) {
                    int rl = wr + a*16 + quad*4 + r;
                    tb[rl*66 + wc + c*16 + l15] = acc[a][c][r] + bias[o0 + rl];
                }
        __syncthreads();
        u16* ohi = role ? kthi : qthi;
        u16* olo = role ? ktlo : qtlo;
        int n = t >> 2, rb = (t & 3)*16;
        #pragma unroll
        for (int g = 0; g < 2; ++g) {
            short8 hi, lo;
            #pragma unroll
            for (int j = 0; j < 8; ++j) {
                float v = tb[(rb + g*8 + j)*66 + n] * scale;
                u16 hb = f2bf(v);
                hi[j] = (short)hb;
                lo[j] = (short)f2bf(v - bf2f(hb));
            }
            int rowg = o0 + rb + g*8;
            size_t ob = ((size_t)(z*4 + (rowg >> 5))*nCols + n0 + n)*32 + (rowg & 31);
            *(short8*)&ohi[ob] = hi;
            *(short8*)&olo[ob] = lo;
        }
    }
}

// ---------------------------------------------------------------------------
// Attention v9: round-16 v8 + branchless online update + explicit
// next-chunk register prefetch (K pass1; K+V pass2).
// ---------------------------------------------------------------------------
__global__ __launch_bounds__(512, 4) void attn4_kernel(
    const u16* __restrict__ qthi, const u16* __restrict__ qtlo,
    const u16* __restrict__ kthi, const u16* __restrict__ ktlo,
    const u16* __restrict__ vthi, int M,
    u16* __restrict__ msghi, u16* __restrict__ msglo, float* __restrict__ p)
{
    __shared__ float pcol[2048];
    __shared__ float obuf[96*66];        // mh-partial merge + msg pack (25.3 KB)
    __shared__ float redm[4][64], redl[4][64];
    __shared__ float rowM[64], rowIV[64];

    const int t = threadIdx.x;
    const int lane = t & 63, wave = t >> 6;
    const int l15 = lane & 15, quad = lane >> 4;
    const int qp = wave & 1, mh = wave >> 1;     // mh 0..3
    const int h = blockIdx.y, z = blockIdx.z;
    const int zh = z*4 + h;
    const int n0 = blockIdx.x * 64;

    for (int i = t; i < M; i += 512) pcol[i] = 0.f;

    short8 qBh[2], qBl[2];
    #pragma unroll
    for (int qt = 0; qt < 2; ++qt) {
        size_t qb = ((size_t)zh*NN + n0 + qp*32 + qt*16 + l15)*32 + quad*8;
        qBh[qt] = *(const short8*)&qthi[qb];
        qBl[qt] = *(const short8*)&qtlo[qb];
    }

    const int nch = M >> 7;
    const size_t kb0 = ((size_t)zh*M + mh*32 + l15)*32 + quad*8;
    const u16* kbh = kthi + kb0;
    const u16* kbl = ktlo + kb0;
    const u16* vb = vthi + ((size_t)zh*32 + l15)*M + mh*32 + quad*8;

    float rm[2] = {-1e30f, -1e30f}, rl[2] = {0.f, 0.f};

    // ---- pass 1: (m,l), 3-term scores, explicit K prefetch ----
    short8 ck0h, ck0l, ck1h, ck1l;
    ck0h = *(const short8*)&kbh[0];
    ck0l = *(const short8*)&kbl[0];
    ck1h = *(const short8*)&kbh[512];
    ck1l = *(const short8*)&kbl[512];
    for (int ch = 0; ch < nch; ++ch) {
        short8 nk0h, nk0l, nk1h, nk1l;
        if (ch + 1 < nch) {
            const int cn = (ch+1)*4096;
            nk0h = *(const short8*)&kbh[cn];
            nk0l = *(const short8*)&kbl[cn];
            nk1h = *(const short8*)&kbh[cn + 512];
            nk1l = *(const short8*)&kbl[cn + 512];
        }
        #pragma unroll
        for (int mt = 0; mt < 2; ++mt) {
            short8 kh = mt ? ck1h : ck0h;
            short8 kl = mt ? ck1l : ck0l;
            __builtin_amdgcn_s_setprio(1);
            f32x4 av[2];
            #pragma unroll
            for (int qt = 0; qt < 2; ++qt) {
                f32x4 a = {0.f,0.f,0.f,0.f};
                a = __builtin_amdgcn_mfma_f32_16x16x32_bf16(kh, qBl[qt], a, 0,0,0);
                a = __builtin_amdgcn_mfma_f32_16x16x32_bf16(kl, qBh[qt], a, 0,0,0);
                a = __builtin_amdgcn_mfma_f32_16x16x32_bf16(kh, qBh[qt], a, 0,0,0);
                av[qt] = a;
            }
            __builtin_amdgcn_s_setprio(0);
            #pragma unroll
            for (int qt = 0; qt < 2; ++qt) {
                f32x4 a = av[qt];
                float bm = fmaxf(fmaxf(a[0],a[1]), fmaxf(a[2],a[3]));
                float bs = fexp2(a[0]-bm)+fexp2(a[1]-bm)+fexp2(a[2]-bm)+fexp2(a[3]-bm);
                // branchless online update (bit-exact vs branchy form)
                float nm = fmaxf(rm[qt], bm);
                rl[qt] = rl[qt]*fexp2(rm[qt]-nm) + bs*fexp2(bm-nm);
                rm[qt] = nm;
            }
        }
        ck0h = nk0h; ck0l = nk0l; ck1h = nk1h; ck1l = nk1l;
    }

    #pragma unroll
    for (int qt = 0; qt < 2; ++qt) {
        #pragma unroll
        for (int off = 16; off <= 32; off <<= 1) {
            float om = __shfl_xor(rm[qt], off);
            float ol = __shfl_xor(rl[qt], off);
            float nm = fmaxf(rm[qt], om);
            rl[qt] = rl[qt]*fexp2(rm[qt]-nm) + ol*fexp2(om-nm);
            rm[qt] = nm;
        }
        if (quad == 0) {
            redm[mh][qp*32 + qt*16 + l15] = rm[qt];
            redl[mh][qp*32 + qt*16 + l15] = rl[qt];
        }
    }
    __syncthreads();
    if (t < 64) {
        float m = redm[0][t], l = redl[0][t];
        #pragma unroll
        for (int w2 = 1; w2 < 4; ++w2) {
            float om = redm[w2][t];
            float nm = fmaxf(m, om);
            l = l*fexp2(m - nm) + redl[w2][t]*fexp2(om - nm);
            m = nm;
        }
        rowM[t] = m;
        rowIV[t] = 1.f / l;
    }
    __syncthreads();
    float myRM[2], myRIV[2];
    #pragma unroll
    for (int qt = 0; qt < 2; ++qt) {
        myRM[qt]  = rowM[qp*32 + qt*16 + l15];
        myRIV[qt] = rowIV[qp*32 + qt*16 + l15];
    }

    // ---- pass 2: probs (3-term), pcol, swapped PV; K+V prefetch ----
    f32x4 oa[2][2];
    #pragma unroll
    for (int qt = 0; qt < 2; ++qt)
        #pragma unroll
        for (int dt = 0; dt < 2; ++dt) oa[qt][dt] = (f32x4){0.f,0.f,0.f,0.f};

    const int aA = (l15 + 32*(quad & 1))*4;
    const int aB = aA + 64;
    const bool mtsel = (quad >= 2);

    ck0h = *(const short8*)&kbh[0];
    ck0l = *(const short8*)&kbl[0];
    ck1h = *(const short8*)&kbh[512];
    ck1l = *(const short8*)&kbl[512];
    short8 cv0 = *(const short8*)&vb[0];
    short8 cv1 = *(const short8*)&vb[(size_t)16*M];

    for (int ch = 0; ch < nch; ++ch) {
        const int m0 = ch << 7;
        short8 nk0h, nk0l, nk1h, nk1l, nv0, nv1;
        if (ch + 1 < nch) {
            const int cn = (ch+1)*4096;
            const int m1 = (ch+1) << 7;
            nk0h = *(const short8*)&kbh[cn];
            nk0l = *(const short8*)&kbl[cn];
            nk1h = *(const short8*)&kbh[cn + 512];
            nk1l = *(const short8*)&kbl[cn + 512];
            nv0 = *(const short8*)&vb[m1];
            nv1 = *(const short8*)&vb[(size_t)16*M + m1];
        }

        float pr[2][2][4];
        #pragma unroll
        for (int mt = 0; mt < 2; ++mt) {
            short8 kh = mt ? ck1h : ck0h;
            short8 kl = mt ? ck1l : ck0l;
            __builtin_amdgcn_s_setprio(1);
            f32x4 av[2];
            #pragma unroll
            for (int qt = 0; qt < 2; ++qt) {
                f32x4 a = {0.f,0.f,0.f,0.f};
                a = __builtin_amdgcn_mfma_f32_16x16x32_bf16(kh, qBl[qt], a, 0,0,0);
                a = __builtin_amdgcn_mfma_f32_16x16x32_bf16(kl, qBh[qt], a, 0,0,0);
                a = __builtin_amdgcn_mfma_f32_16x16x32_bf16(kh, qBh[qt], a, 0,0,0);
                av[qt] = a;
            }
            __builtin_amdgcn_s_setprio(0);
            #pragma unroll
            for (int qt = 0; qt < 2; ++qt)
                #pragma unroll
                for (int r = 0; r < 4; ++r)
                    pr[qt][mt][r] = fexp2(av[qt][r] - myRM[qt]);
        }

        #pragma unroll
        for (int mt = 0; mt < 2; ++mt)
            #pragma unroll
            for (int r = 0; r < 4; ++r) {
                float ps = pr[0][mt][r]*myRIV[0] + pr[1][mt][r]*myRIV[1];
                ps += __shfl_xor(ps, 1);
                ps += __shfl_xor(ps, 2);
                ps += __shfl_xor(ps, 4);
                ps += __shfl_xor(ps, 8);
                if (l15 == 0)
                    atomicAdd(&pcol[m0 + mh*32 + mt*16 + quad*4 + r], ps);
            }

        #pragma unroll
        for (int qt = 0; qt < 2; ++qt) {
            unsigned pk00 = cvtpk_bf16(pr[qt][0][0], pr[qt][0][1]);
            unsigned pk01 = cvtpk_bf16(pr[qt][0][2], pr[qt][0][3]);
            unsigned pk10 = cvtpk_bf16(pr[qt][1][0], pr[qt][1][1]);
            unsigned pk11 = cvtpk_bf16(pr[qt][1][2], pr[qt][1][3]);
            unsigned a0 = (unsigned)__builtin_amdgcn_ds_bpermute(aA, (int)pk00);
            unsigned a1 = (unsigned)__builtin_amdgcn_ds_bpermute(aA, (int)pk01);
            unsigned a2 = (unsigned)__builtin_amdgcn_ds_bpermute(aA, (int)pk10);
            unsigned a3 = (unsigned)__builtin_amdgcn_ds_bpermute(aA, (int)pk11);
            unsigned b0 = (unsigned)__builtin_amdgcn_ds_bpermute(aB, (int)pk00);
            unsigned b1 = (unsigned)__builtin_amdgcn_ds_bpermute(aB, (int)pk01);
            unsigned b2 = (unsigned)__builtin_amdgcn_ds_bpermute(aB, (int)pk10);
            unsigned b3 = (unsigned)__builtin_amdgcn_ds_bpermute(aB, (int)pk11);
            union { unsigned u[4]; short8 s; } fb;
            fb.u[0] = mtsel ? a2 : a0;
            fb.u[1] = mtsel ? a3 : a1;
            fb.u[2] = mtsel ? b2 : b0;
            fb.u[3] = mtsel ? b3 : b1;
            __builtin_amdgcn_s_setprio(1);
            oa[qt][0] = __builtin_amdgcn_mfma_f32_16x16x32_bf16(cv0, fb.s, oa[qt][0], 0,0,0);
            oa[qt][1] = __builtin_amdgcn_mfma_f32_16x16x32_bf16(cv1, fb.s, oa[qt][1], 0,0,0);
            __builtin_amdgcn_s_setprio(0);
        }
        ck0h = nk0h; ck0l = nk0l; ck1h = nk1h; ck1l = nk1l;
        cv0 = nv0; cv1 = nv1;
    }

    if (mh > 0) {
        #pragma unroll
        for (int qt = 0; qt < 2; ++qt)
            #pragma unroll
            for (int dt = 0; dt < 2; ++dt)
                #pragma unroll
                for (int r = 0; r < 4; ++r) {
                    int q = qp*32 + qt*16 + l15;
                    int d = dt*16 + quad*4 + r;
                    obuf[((mh-1)*32 + d)*66 + q] = oa[qt][dt][r];
                }
    }
    __syncthreads();
    if (mh == 0) {
        #pragma unroll
        for (int qt = 0; qt < 2; ++qt)
            #pragma unroll
            for (int dt = 0; dt < 2; ++dt)
                #pragma unroll
                for (int r = 0; r < 4; ++r) {
                    int q = qp*32 + qt*16 + l15;
                    int d = dt*16 + quad*4 + r;
                    float v = oa[qt][dt][r];
                    #pragma unroll
                    for (int w2 = 0; w2 < 3; ++w2)
                        v += obuf[(w2*32 + d)*66 + q];
                    obuf[d*66 + q] = v * myRIV[qt];
                }
    }
    __syncthreads();
    {
        int tt = t & 255;
        int n = tt >> 2, i8 = (tt & 3)*8;
        short8 o8;
        if (t < 256) {
            #pragma unroll
            for (int j = 0; j < 8; ++j) o8[j] = (short)f2bf(obuf[(i8+j)*66 + n]);
            *(short8*)&msghi[((size_t)z*NN + n0 + n)*128 + h*32 + i8] = o8;
        } else {
            #pragma unroll
            for (int j = 0; j < 8; ++j) {
                float v = obuf[(i8+j)*66 + n];
                u16 hb = f2bf(v);
                o8[j] = (short)f2bf(v - bf2f(hb));
            }
            *(short8*)&msglo[((size_t)z*NN + n0 + n)*128 + h*32 + i8] = o8;
        }
    }
    for (int i = t; i < M; i += 512)
        atomicAdd(&p[(size_t)z*NN + i], pcol[i]*0.25f);
}

// ---------------------------------------------------------------------------
// W1: z = W1a x + W1b' msg + b1' -> TRANSPOSED zf_t [z][n][256] (fp32) via
// LDS transpose + instnorm stats atomics.
// ---------------------------------------------------------------------------
__global__ __launch_bounds__(256) void w1_kernel(
    const u16* __restrict__ W1h, const u16* __restrict__ W1l,
    const float* __restrict__ b1,
    const u16* __restrict__ xphi, const u16* __restrict__ xplo,
    const u16* __restrict__ m2hi, const u16* __restrict__ m2lo,
    float* __restrict__ zft, float* __restrict__ gsum, float* __restrict__ gsq)
{
    __shared__ u16 gsm[10240];
    u16* As0 = gsm;  u16* As1 = gsm + 2560;
    u16* Bs0 = gsm + 5120; u16* Bs1 = gsm + 7680;
    float* tb = (float*)gsm;                 // [64][66] after gcore

    const int z = blockIdx.z, o0 = blockIdx.y*64, n0 = blockIdx.x*64;
    const int t = threadIdx.x;
    const int lane = t & 63, w = t >> 6;
    const int l15 = lane & 15, quad = lane >> 4;
    const int wr = (w & 1)*32, wc = (w >> 1)*32;

    f32x4 acc[2][2];
    #pragma unroll
    for (int a = 0; a < 2; ++a)
        #pragma unroll
        for (int c = 0; c < 2; ++c) acc[a][c] = (f32x4){0.f,0.f,0.f,0.f};
    gcore(As0, As1, Bs0, Bs1, W1h, W1l, o0, 256,
          xphi, xplo, 128, m2hi, m2lo, 128, 128,
          (size_t)z*NN, n0, nullptr, t, acc);

    float ssum[2][4], ssq[2][4];
    #pragma unroll
    for (int a = 0; a < 2; ++a)
        #pragma unroll
        for (int r = 0; r < 4; ++r) { ssum[a][r] = 0.f; ssq[a][r] = 0.f; }
    #pragma unroll
    for (int a = 0; a < 2; ++a)
        #pragma unroll
        for (int c = 0; c < 2; ++c)
            #pragma unroll
            for (int r = 0; r < 4; ++r) {
                int rl = wr + a*16 + quad*4 + r;
                int cl = wc + c*16 + l15;
                float v = acc[a][c][r] + b1[o0 + rl];
                tb[rl*66 + cl] = v;
                ssum[a][r] += v;
                ssq[a][r] = fmaf(v, v, ssq[a][r]);
            }
    #pragma unroll
    for (int a = 0; a < 2; ++a)
        #pragma unroll
        for (int r = 0; r < 4; ++r) {
            float s = ssum[a][r], q2 = ssq[a][r];
            #pragma unroll
            for (int o = 1; o < 16; o <<= 1) {
                s  += __shfl_xor(s, o);
                q2 += __shfl_xor(q2, o);
            }
            if (l15 == 0) {
                int row = o0 + wr + a*16 + quad*4 + r;
                atomicAdd(&gsum[z*256 + row], s);
                atomicAdd(&gsq[z*256 + row], q2);
            }
        }
    __syncthreads();
    // transposed write: zf_t[(z*NN + n0+n)*256 + o0 + c]
    int n = t >> 2, rb = (t & 3)*16;
    #pragma unroll
    for (int g = 0; g < 2; ++g) {
        float4 v0, v1;
        v0.x = tb[(rb + g*8 + 0)*66 + n];
        v0.y = tb[(rb + g*8 + 1)*66 + n];
        v0.z = tb[(rb + g*8 + 2)*66 + n];
        v0.w = tb[(rb + g*8 + 3)*66 + n];
        v1.x = tb[(rb + g*8 + 4)*66 + n];
        v1.y = tb[(rb + g*8 + 5)*66 + n];
        v1.z = tb[(rb + g*8 + 6)*66 + n];
        v1.w = tb[(rb + g*8 + 7)*66 + n];
        float* dst = &zft[((size_t)z*NN + n0 + n)*256 + o0 + rb + g*8];
        *(float4*)dst = v0;
        *(float4*)(dst + 4) = v1;
    }
}

// ---------------------------------------------------------------------------
// W2: x += W2·relu(instnorm(z)) + b2 (fp32), instnorm inline from zf_t,
// and refresh x planes (unless last layer). hrepack fused away.
// ---------------------------------------------------------------------------
__global__ __launch_bounds__(256) void w2_kernel(
    const u16* __restrict__ W2h, const u16* __restrict__ W2l,
    const float* __restrict__ b2,
    const float* __restrict__ zft, const float* __restrict__ gsum,
    const float* __restrict__ gsq,
    float* __restrict__ out, u16* __restrict__ xphi, u16* __restrict__ xplo,
    int writeplanes)
{
    __shared__ u16 gsm[10240];
    __shared__ float meanL[256], ivL[256];
    u16* As0 = gsm;  u16* As1 = gsm + 2560;
    u16* Bs0 = gsm + 5120; u16* Bs1 = gsm + 7680;
    float* tb = (float*)gsm;

    const int z = blockIdx.z, o0 = blockIdx.y*64, n0 = blockIdx.x*64;
    const int t = threadIdx.x;
    const int lane = t & 63, w = t >> 6;
    const int l15 = lane & 15, quad = lane >> 4;
    const int wr = (w & 1)*32, wc = (w >> 1)*32;

    {
        float mean = gsum[z*256 + t] * (1.f/NN);
        float var  = gsq[z*256 + t] * (1.f/NN) - mean*mean;
        meanL[t] = mean;
        ivL[t] = rsqrtf(var + IN_EPS);
    }
    __syncthreads();

    f32x4 acc[2][2];
    #pragma unroll
    for (int a = 0; a < 2; ++a)
        #pragma unroll
        for (int c = 0; c < 2; ++c) acc[a][c] = (f32x4){0.f,0.f,0.f,0.f};
    gcore_w2(As0, As1, Bs0, Bs1, W2h, W2l, o0,
             zft, meanL, ivL, (size_t)z*NN, n0, t, acc);

    #pragma unroll
    for (int a = 0; a < 2; ++a)
        #pragma unroll
        for (int c = 0; c < 2; ++c)
            #pragma unroll
            for (int r = 0; r < 4; ++r) {
                int rl = wr + a*16 + quad*4 + r;
                int rowg = o0 + rl;
                int n = n0 + wc + c*16 + l15;
                size_t oi = ((size_t)z*128 + rowg)*NN + n;
                float v = acc[a][c][r] + b2[rowg] + out[oi];
                out[oi] = v;
                tb[rl*66 + wc + c*16 + l15] = v;
            }
    __syncthreads();
    if (writeplanes) {
        int n = t >> 2, rb = (t & 3)*16;
        #pragma unroll
        for (int g = 0; g < 2; ++g) {
            short8 hi, lo;
            #pragma unroll
            for (int j = 0; j < 8; ++j) {
                float v = tb[(rb + g*8 + j)*66 + n];
                u16 hb = f2bf(v);
                hi[j] = (short)hb;
                lo[j] = (short)f2bf(v - bf2f(hb));
            }
            size_t ob = ((size_t)z*NN + n0 + n)*128 + o0 + rb + g*8;
            *(short8*)&xphi[ob] = hi;
            *(short8*)&xplo[ob] = lo;
        }
    }
}

// ---------------------------------------------------------------------------
__global__ __launch_bounds__(256) void rank_kernel(
    const float* __restrict__ p, int* __restrict__ rank, int M)
{
    int zz = blockIdx.y;
    __shared__ float pv[2048];
    for (int i = threadIdx.x; i < M; i += 256) pv[i] = p[(size_t)zz*NN + i];
    __syncthreads();
    int i = blockIdx.x * 256 + threadIdx.x;
    if (i < M) {
        float pi = pv[i];
        int r = 0;
        for (int j = 0; j < M; ++j) {
            float pj = pv[j];
            r += (pj > pi) ? 1 : ((pj == pi && j < i) ? 1 : 0);
        }
        rank[zz*NN + i] = r;
    }
}

__global__ __launch_bounds__(256) void select_kernel(
    const int* __restrict__ rank, int* __restrict__ idx0, int* __restrict__ idx1,
    int M, int k, int cross)
{
    int z = blockIdx.x;
    int st = z >> 1, b = z & 1;
    int ts = cross ? 1 - st : st;
    int* idx = (ts ? idx1 : idx0) + b * NN;
    const int* rk = rank + z * NN;
    __shared__ int sel[2048], idv[2048], sa[2048], sb[2048];
    int t = threadIdx.x;
    for (int i = t; i < M; i += 256) {
        int s = rk[i] < k ? 1 : 0;
        sel[i] = s;
        sa[i] = s;
        idv[i] = idx[i];
    }
    __syncthreads();
    int* src = sa; int* dst = sb;
    for (int off = 1; off < M; off <<= 1) {
        for (int i = t; i < M; i += 256)
            dst[i] = src[i] + (i >= off ? src[i - off] : 0);
        __syncthreads();
        int* tmp = src; src = dst; dst = tmp;
    }
    for (int i = t; i < M; i += 256)
        if (sel[i]) idx[src[i] - 1] = idv[i];
}

// ---------------------------------------------------------------------------
extern "C" void kernel_launch(void* const* d_in, const int* in_sizes, int n_in,
                              void* d_out, int out_size, void* d_ws, size_t ws_size,
                              hipStream_t stream)
{
    const float* x0in = (const float*)d_in[0];
    const float* x1in = (const float*)d_in[1];
    const float* Wq = (const float*)d_in[2];
    const float* bq = (const float*)d_in[3];
    const float* Wk = (const float*)d_in[4];
    const float* bk = (const float*)d_in[5];
    const float* Wv = (const float*)d_in[6];
    const float* bv = (const float*)d_in[7];
    const float* Wm = (const float*)d_in[8];
    const float* bm = (const float*)d_in[9];
    const float* W1 = (const float*)d_in[10];
    const float* b1 = (const float*)d_in[11];
    const float* W2 = (const float*)d_in[12];
    const float* b2 = (const float*)d_in[13];

    float* out = (float*)d_out;
    float* ws  = (float*)d_ws;

    const size_t U = 1048576;
    u16* ub   = (u16*)ws;
    u16* xphi = ub;            u16* xplo = ub + U;
    u16* qthi = ub + 2*U;      u16* qtlo = ub + 3*U;
    u16* kthi = ub + 4*U;      u16* ktlo = ub + 5*U;
    u16* vthi = ub + 6*U;
    u16* msghi = ub + 7*U;     u16* msglo = ub + 8*U;
    u16* whi  = ub + 15*U;     u16* wlo = whi + 655360;
    float* zft = (float*)(ub + 2*U);                       // aliases qt/kt (8 MB)
    float* ft = (float*)(wlo + 655360);
    float* bqp = ft;           float* bkp = ft + 512;      float* bvp = ft + 1024;
    float* gsum = ft + 1536;   float* gsq = ft + 2560;
    float* p = ft + 3584;                                  // [4][NN]
    int* idx0 = (int*)(p + 4*NN);
    int* idx1 = idx0 + NB*NN;
    int* rankb = idx1 + NB*NN;
    float* b1p = (float*)(rankb + 4*NN);                   // [4][256]

    init_kernel<<<BDN/4/256, 256, 0, stream>>>(x0in, x1in, out, idx0, idx1);
    wrepack2_kernel<<<2570, 256, 0, stream>>>(Wq, Wk, Wv, Wm, W1, W2, bq, bk, bv,
                                              bm, b1, whi, wlo, bqp, bkp, bvp, b1p);
    repack_xh_kernel<<<dim3(32, 16), 256, 0, stream>>>(out, xphi, xplo);

    const int Ms[4] = {2048, 1024, 512, 256};
    for (int l = 0; l < 4; ++l) {
        int M = Ms[l];
        int k_new = (M/2 < 128) ? 128 : M/2;
        int cross = l & 1;
        size_t lw = (size_t)l * 163840;
        const u16* Wlh = whi + lw;  const u16* Wll = wlo + lw;

        qkv_kernel<<<dim3(64 + 4*(M/64), 1, 4), 256, 0, stream>>>(
            Wlh, Wll, bqp + l*128, bkp + l*128, bvp + l*128,
            xphi, xplo, idx0, idx1, cross, M,
            qthi, qtlo, kthi, ktlo, vthi, p, gsum, gsq);

        attn4_kernel<<<dim3(32, NH, 4), 512, 0, stream>>>(
            qthi, qtlo, kthi, ktlo, vthi, M, msghi, msglo, p);

        w1_kernel<<<dim3(32, 4, 4), 256, 0, stream>>>(
            Wlh + 65536, Wll + 65536, b1p + l*256,
            xphi, xplo, msghi, msglo, zft, gsum, gsq);

        w2_kernel<<<dim3(32, 2, 4), 256, 0, stream>>>(
            Wlh + 131072, Wll + 131072, b2 + l*128,
            zft, gsum, gsq, out, xphi, xplo, (l < 3) ? 1 : 0);

        rank_kernel<<<dim3((M+255)/256, 4), 256, 0, stream>>>(p, rankb, M);
        select_kernel<<<4, 256, 0, stream>>>(rankb, idx0, idx1, M, k_new, cross);
    }
}

// Round 10
// 505.581 us; speedup vs baseline: 1.0705x; 1.0705x over previous
//
#include <hip/hip_runtime.h>
#include <cstdint>
#include <cstddef>

// ---------------------------------------------------------------------------
// SDHGNN round 18: round-16 base + attn4 pass-2 LDS-pipe relief.
//  - pcol 16-lane reduce via DPP row_ror (VALU pipe) instead of shfl_xor
//    (ds_swizzle on the CU-shared LDS pipe): 32 LDS-pipe ops/chunk -> 0.
//  - pcol split per-qp (two buffers, +8KB LDS): LDS atomicAdd -> plain store.
//  Pass-2 LDS-pipe ops 56 -> 24 per wave per chunk (bpermute 16 + store 8).
//  Everything else (incl. attn4 pass 1) byte-identical to round 16.
// ---------------------------------------------------------------------------

#define NB 2
#define ND 128
#define NH 4
#define NN 2048
#define ND2 256
#define DN (ND*NN)
#define BDN (NB*DN)
// (1/sqrt(32)) * log2(e): scores produced directly in exp2 domain.
#define QK_SCALE 0.2550348623f
#define IN_EPS 1e-3f

typedef unsigned short u16;
typedef __attribute__((ext_vector_type(8))) short short8;
typedef __attribute__((ext_vector_type(4))) float f32x4;

__device__ __forceinline__ u16 f2bf(float f) {
    unsigned u = __float_as_uint(f);
    return (u16)((u + 0x7fffu + ((u >> 16) & 1u)) >> 16);
}
__device__ __forceinline__ float bf2f(u16 h) {
    return __uint_as_float(((unsigned)h) << 16);
}
__device__ __forceinline__ float fexp2(float x) {
#if __has_builtin(__builtin_amdgcn_exp2f)
    return __builtin_amdgcn_exp2f(x);
#else
    return exp2f(x);
#endif
}
__device__ __forceinline__ unsigned cvtpk_bf16(float a, float b) {
    unsigned r;
    asm("v_cvt_pk_bf16_f32 %0, %1, %2" : "=v"(r) : "v"(a), "v"(b));
    return r;
}
// DPP row-rotate (within 16-lane rows) on the VALU pipe; N in {1,2,4,8}.
#define ROR16F(x, N) __int_as_float(__builtin_amdgcn_update_dpp( \
    0, __float_as_int(x), 0x120 + (N), 0xF, 0xF, true))

// ---------------------------------------------------------------------------
__global__ __launch_bounds__(256) void init_kernel(
    const float* __restrict__ x0in, const float* __restrict__ x1in,
    float* __restrict__ out, int* __restrict__ idx0, int* __restrict__ idx1)
{
    int tid = blockIdx.x * 256 + threadIdx.x;
    const float4* a = (const float4*)x0in;
    const float4* b = (const float4*)x1in;
    float4* o = (float4*)out;
    o[tid] = a[tid];
    o[BDN/4 + tid] = b[tid];
    if (tid < NB*NN) {
        int v = tid & (NN-1);
        idx0[tid] = v;
        idx1[tid] = v;
    }
}

// ---------------------------------------------------------------------------
// weights -> bf16 hi/lo planes with permutations:
//   Wq/Wk/Wv rows permuted o' = h*32+i; Wm cols permuted; W1 cols 0..127
//   copied, cols 128..255 FUSED = W1[:,128:]·Wm (col-permuted); W2 unchanged.
// Tail: bias permutes + b1' = b1 + W1[:,128:]·bm.
// ---------------------------------------------------------------------------
__global__ __launch_bounds__(256) void wrepack2_kernel(
    const float* __restrict__ Wq, const float* __restrict__ Wk,
    const float* __restrict__ Wv, const float* __restrict__ Wm,
    const float* __restrict__ W1, const float* __restrict__ W2,
    const float* __restrict__ bq, const float* __restrict__ bk,
    const float* __restrict__ bv, const float* __restrict__ bm,
    const float* __restrict__ b1,
    u16* __restrict__ whi, u16* __restrict__ wlo,
    float* __restrict__ bqp, float* __restrict__ bkp, float* __restrict__ bvp,
    float* __restrict__ b1p)
{
    int e = blockIdx.x * 256 + threadIdx.x;
    if (e < 655360) {
        int l = e / 163840, r = e - l*163840;
        float v;
        if (r < 49152) {
            int m = r >> 14;
            int rr = r & 16383;
            int o = rr >> 7, c = rr & 127;
            int so = (o & 31)*4 + (o >> 5);
            const float* W = (m == 0) ? Wq : ((m == 1) ? Wk : Wv);
            v = W[l*16384 + so*128 + c];
        } else if (r < 65536) {
            int rr = r - 49152;
            int o = rr >> 7, c = rr & 127;
            int sc = (c & 31)*4 + (c >> 5);
            v = Wm[l*16384 + o*128 + sc];
        } else if (r < 131072) {
            int rr = r - 65536;              // o*256 + c
            int c = rr & 255;
            if (c < 128) {
                v = W1[l*65536 + rr];
            } else {
                // fused: W1b'[o][c-128] = sum_k W1[o][128+k] * Wm[k][sc]
                int o = rr >> 8, cc = c - 128;
                int sc = (cc & 31)*4 + (cc >> 5);
                const float* w1row = &W1[l*65536 + o*256 + 128];
                const float* wmcol = &Wm[l*16384 + sc];
                float acc = 0.f;
                #pragma unroll 4
                for (int k = 0; k < 128; ++k)
                    acc = fmaf(w1row[k], wmcol[k*128], acc);
                v = acc;
            }
        }
        else                   v = W2[l*32768 + r - 131072];
        u16 hb = f2bf(v);
        whi[e] = hb;
        wlo[e] = f2bf(v - bf2f(hb));
    } else if (e < 656896) {
        int eb = e - 655360;
        int l = eb / 384, rr = eb % 384;
        int which = rr >> 7, o = rr & 127;
        int so = (o & 31)*4 + (o >> 5);
        float v = (which == 0 ? bq : (which == 1 ? bk : bv))[l*128 + so];
        (which == 0 ? bqp : (which == 1 ? bkp : bvp))[l*128 + o] = v;
    } else if (e < 657920) {
        // b1'[l][o] = b1[l][o] + sum_k W1[o][128+k] * bm[k]
        int idx = e - 656896;
        int l = idx >> 8, o = idx & 255;
        const float* w1row = &W1[l*65536 + o*256 + 128];
        const float* bmv = &bm[l*128];
        float acc = b1[l*256 + o];
        #pragma unroll 4
        for (int k = 0; k < 128; ++k)
            acc = fmaf(w1row[k], bmv[k], acc);
        b1p[l*256 + o] = acc;
    }
}

// ---------------------------------------------------------------------------
// fp32 [z][128][NN] -> bf16 hi/lo planes [z][n][128] (initial x planes)
// ---------------------------------------------------------------------------
__global__ __launch_bounds__(256) void repack_xh_kernel(
    const float* __restrict__ in, u16* __restrict__ ohi, u16* __restrict__ olo)
{
    __shared__ float tile[32][68];
    int z = blockIdx.y >> 2, cg = blockIdx.y & 3;
    int n0 = blockIdx.x * 64;
    int t = threadIdx.x;
    {
        int i = t >> 3, nc = (t & 7) * 8;
        const float* src = &in[((size_t)z*128 + cg*32 + i)*NN + n0 + nc];
        float4 a = *(const float4*)src;
        float4 b = *(const float4*)(src + 4);
        tile[i][nc+0]=a.x; tile[i][nc+1]=a.y; tile[i][nc+2]=a.z; tile[i][nc+3]=a.w;
        tile[i][nc+4]=b.x; tile[i][nc+5]=b.y; tile[i][nc+6]=b.z; tile[i][nc+7]=b.w;
    }
    __syncthreads();
    int n = t >> 2, c8 = (t & 3) * 8;
    short8 hi, lo;
    #pragma unroll
    for (int j = 0; j < 8; ++j) {
        float v = tile[c8 + j][n];
        u16 h = f2bf(v);
        hi[j] = (short)h;
        lo[j] = (short)f2bf(v - bf2f(h));
    }
    size_t ob = ((size_t)z*NN + n0 + n)*128 + cg*32 + c8;
    *(short8*)&ohi[ob] = hi;
    *(short8*)&olo[ob] = lo;
}

// ---------------------------------------------------------------------------
// shared 64x64 GEMM core, split-bf16 3-term, K-chunk 32, 4 waves 2x2 subtiles.
// T14: next K-chunk's global loads issued into registers during compute;
// only reg->LDS writes sit between barriers. (unchanged)
// ---------------------------------------------------------------------------
__device__ __forceinline__ void gcore(
    u16* As0, u16* As1, u16* Bs0, u16* Bs1,
    const u16* __restrict__ Whi, const u16* __restrict__ Wlo, int o0, int Cin,
    const u16* __restrict__ B1hi, const u16* __restrict__ B1lo, int s1,
    const u16* __restrict__ B2hi, const u16* __restrict__ B2lo, int s2, int split,
    size_t brow, int n0, const int* __restrict__ idxp, int t, f32x4 acc[2][2])
{
    const int lane = t & 63, w = t >> 6;
    const int l15 = lane & 15, quad = lane >> 4;
    const int wr = (w & 1)*32, wc = (w >> 1)*32;
    const int ao = t >> 2, ak = (t & 3)*8;
    int grow = n0 + ao;
    if (idxp) grow = idxp[grow];

    short8 rA0, rA1, rB0, rB1;
    {
        size_t wa = (size_t)(o0 + ao)*Cin + ak;
        rA0 = *(const short8*)&Whi[wa];
        rA1 = *(const short8*)&Wlo[wa];
        int c = ak;
        const u16 *ph, *pl; size_t off;
        if (c < split) { ph = B1hi; pl = B1lo; off = (brow + grow)*s1 + c; }
        else { ph = B2hi; pl = B2lo; off = (brow + grow)*s2 + (c - split); }
        rB0 = *(const short8*)&ph[off];
        rB1 = *(const short8*)&pl[off];
    }
    for (int kc = 0; kc < Cin; kc += 32) {
        __syncthreads();
        *(short8*)&As0[ao*40 + ak] = rA0;
        *(short8*)&As1[ao*40 + ak] = rA1;
        *(short8*)&Bs0[ao*40 + ak] = rB0;
        *(short8*)&Bs1[ao*40 + ak] = rB1;
        if (kc + 32 < Cin) {
            size_t wa = (size_t)(o0 + ao)*Cin + kc + 32 + ak;
            rA0 = *(const short8*)&Whi[wa];
            rA1 = *(const short8*)&Wlo[wa];
            int c = kc + 32 + ak;
            const u16 *ph, *pl; size_t off;
            if (c < split) { ph = B1hi; pl = B1lo; off = (brow + grow)*s1 + c; }
            else { ph = B2hi; pl = B2lo; off = (brow + grow)*s2 + (c - split); }
            rB0 = *(const short8*)&ph[off];
            rB1 = *(const short8*)&pl[off];
        }
        __syncthreads();
        short8 Ah[2], Al[2], Bh[2], Bl[2];
        #pragma unroll
        for (int a = 0; a < 2; ++a) {
            Ah[a] = *(const short8*)&As0[(wr + a*16 + l15)*40 + quad*8];
            Al[a] = *(const short8*)&As1[(wr + a*16 + l15)*40 + quad*8];
        }
        #pragma unroll
        for (int c = 0; c < 2; ++c) {
            Bh[c] = *(const short8*)&Bs0[(wc + c*16 + l15)*40 + quad*8];
            Bl[c] = *(const short8*)&Bs1[(wc + c*16 + l15)*40 + quad*8];
        }
        #pragma unroll
        for (int a = 0; a < 2; ++a)
            #pragma unroll
            for (int c = 0; c < 2; ++c) {
                acc[a][c] = __builtin_amdgcn_mfma_f32_16x16x32_bf16(Ah[a], Bl[c], acc[a][c], 0,0,0);
                acc[a][c] = __builtin_amdgcn_mfma_f32_16x16x32_bf16(Al[a], Bh[c], acc[a][c], 0,0,0);
                acc[a][c] = __builtin_amdgcn_mfma_f32_16x16x32_bf16(Ah[a], Bh[c], acc[a][c], 0,0,0);
            }
    }
    __syncthreads();
}

// ---------------------------------------------------------------------------
// gcore variant for w2: B comes from fp32 zf_t [z][n][256] with inline
// instnorm+relu+bf16 split (stats from LDS). A path / MFMA identical.
// ---------------------------------------------------------------------------
__device__ __forceinline__ void gcore_w2(
    u16* As0, u16* As1, u16* Bs0, u16* Bs1,
    const u16* __restrict__ Whi, const u16* __restrict__ Wlo, int o0,
    const float* __restrict__ zft, const float* __restrict__ meanL,
    const float* __restrict__ ivL,
    size_t brow, int n0, int t, f32x4 acc[2][2])
{
    const int Cin = 256;
    const int lane = t & 63, w = t >> 6;
    const int l15 = lane & 15, quad = lane >> 4;
    const int wr = (w & 1)*32, wc = (w >> 1)*32;
    const int ao = t >> 2, ak = (t & 3)*8;
    const float* brows = &zft[(brow + n0 + ao)*256];

    short8 rA0, rA1, rBh, rBl;
    {
        size_t wa = (size_t)(o0 + ao)*Cin + ak;
        rA0 = *(const short8*)&Whi[wa];
        rA1 = *(const short8*)&Wlo[wa];
        float4 f0 = *(const float4*)&brows[ak];
        float4 f1 = *(const float4*)&brows[ak + 4];
        float f[8] = {f0.x,f0.y,f0.z,f0.w,f1.x,f1.y,f1.z,f1.w};
        #pragma unroll
        for (int j = 0; j < 8; ++j) {
            float v = (f[j] - meanL[ak + j]) * ivL[ak + j];
            v = v > 0.f ? v : 0.f;
            u16 hb = f2bf(v);
            rBh[j] = (short)hb;
            rBl[j] = (short)f2bf(v - bf2f(hb));
        }
    }
    for (int kc = 0; kc < Cin; kc += 32) {
        __syncthreads();
        *(short8*)&As0[ao*40 + ak] = rA0;
        *(short8*)&As1[ao*40 + ak] = rA1;
        *(short8*)&Bs0[ao*40 + ak] = rBh;
        *(short8*)&Bs1[ao*40 + ak] = rBl;
        float4 f0n, f1n;
        const bool more = (kc + 32 < Cin);
        if (more) {
            size_t wa = (size_t)(o0 + ao)*Cin + kc + 32 + ak;
            rA0 = *(const short8*)&Whi[wa];
            rA1 = *(const short8*)&Wlo[wa];
            f0n = *(const float4*)&brows[kc + 32 + ak];
            f1n = *(const float4*)&brows[kc + 32 + ak + 4];
        }
        __syncthreads();
        short8 Ah[2], Al[2], Bh[2], Bl[2];
        #pragma unroll
        for (int a = 0; a < 2; ++a) {
            Ah[a] = *(const short8*)&As0[(wr + a*16 + l15)*40 + quad*8];
            Al[a] = *(const short8*)&As1[(wr + a*16 + l15)*40 + quad*8];
        }
        #pragma unroll
        for (int c = 0; c < 2; ++c) {
            Bh[c] = *(const short8*)&Bs0[(wc + c*16 + l15)*40 + quad*8];
            Bl[c] = *(const short8*)&Bs1[(wc + c*16 + l15)*40 + quad*8];
        }
        #pragma unroll
        for (int a = 0; a < 2; ++a)
            #pragma unroll
            for (int c = 0; c < 2; ++c) {
                acc[a][c] = __builtin_amdgcn_mfma_f32_16x16x32_bf16(Ah[a], Bl[c], acc[a][c], 0,0,0);
                acc[a][c] = __builtin_amdgcn_mfma_f32_16x16x32_bf16(Al[a], Bh[c], acc[a][c], 0,0,0);
                acc[a][c] = __builtin_amdgcn_mfma_f32_16x16x32_bf16(Ah[a], Bh[c], acc[a][c], 0,0,0);
            }
        if (more) {
            float f[8] = {f0n.x,f0n.y,f0n.z,f0n.w,f1n.x,f1n.y,f1n.z,f1n.w};
            #pragma unroll
            for (int j = 0; j < 8; ++j) {
                int cc = kc + 32 + ak + j;
                float v = (f[j] - meanL[cc]) * ivL[cc];
                v = v > 0.f ? v : 0.f;
                u16 hb = f2bf(v);
                rBh[j] = (short)hb;
                rBl[j] = (short)f2bf(v - bf2f(hb));
            }
        }
    }
    __syncthreads();
}

// ---------------------------------------------------------------------------
// Fused QKV (unchanged).
// ---------------------------------------------------------------------------
__global__ __launch_bounds__(256) void qkv_kernel(
    const u16* __restrict__ Whi, const u16* __restrict__ Wlo,
    const float* __restrict__ bqp, const float* __restrict__ bkp,
    const float* __restrict__ bvp,
    const u16* __restrict__ xphi, const u16* __restrict__ xplo,
    const int* __restrict__ idx0, const int* __restrict__ idx1,
    int cross, int M,
    u16* __restrict__ qthi, u16* __restrict__ qtlo,
    u16* __restrict__ kthi, u16* __restrict__ ktlo,
    u16* __restrict__ vthi, float* __restrict__ p,
    float* __restrict__ gsum, float* __restrict__ gsq)
{
    __shared__ u16 gsm[10240];
    u16* As0 = gsm;  u16* As1 = gsm + 2560;
    u16* Bs0 = gsm + 5120; u16* Bs1 = gsm + 7680;
    float* tb = (float*)gsm;                 // [64][66]

    const int z = blockIdx.z;
    const int bx = blockIdx.x;
    const int t = threadIdx.x;
    const int lane = t & 63, w = t >> 6;
    const int l15 = lane & 15, quad = lane >> 4;
    const int wr = (w & 1)*32, wc = (w >> 1)*32;

    int role, o0, n0, nCols;
    const u16 *Wbh, *Wbl;
    const float* bias;
    if (bx < 64) {
        role = 0; o0 = (bx & 1)*64; n0 = (bx >> 1)*64; nCols = NN;
        Wbh = Whi; Wbl = Wlo; bias = bqp;
        if (t < 32) p[(size_t)z*NN + bx*32 + t] = 0.f;
        if (bx == 0) { gsum[z*256 + t] = 0.f; gsq[z*256 + t] = 0.f; }
    } else {
        int e = bx - 64;
        int kt = M >> 6;
        int ct = e % kt, rt = e / kt;
        n0 = ct*64; nCols = M;
        if (rt < 2) { role = 1; o0 = rt*64; Wbh = Whi+16384; Wbl = Wlo+16384; bias = bkp; }
        else        { role = 2; o0 = (rt-2)*64; Wbh = Whi+32768; Wbl = Wlo+32768; bias = bvp; }
    }
    size_t brow = (size_t)z * NN;
    const int* idxp = nullptr;
    if (role != 0) {
        int ss = cross ? 1 - (z >> 1) : (z >> 1);
        brow = (size_t)(ss*2 + (z & 1)) * NN;
        idxp = (ss ? idx1 : idx0) + (z & 1)*NN;
    }

    f32x4 acc[2][2];
    #pragma unroll
    for (int a = 0; a < 2; ++a)
        #pragma unroll
        for (int c = 0; c < 2; ++c) acc[a][c] = (f32x4){0.f,0.f,0.f,0.f};

    gcore(As0, As1, Bs0, Bs1, Wbh, Wbl, o0, 128,
          xphi, xplo, 128, xphi, xplo, 128, 128, brow, n0, idxp, t, acc);

    if (role == 2) {
        #pragma unroll
        for (int a = 0; a < 2; ++a)
            #pragma unroll
            for (int c = 0; c < 2; ++c)
                #pragma unroll
                for (int r = 0; r < 4; ++r) {
                    int row = o0 + wr + a*16 + quad*4 + r;
                    int m = n0 + wc + c*16 + l15;
                    float v = acc[a][c][r] + bias[row];
                    vthi[((size_t)(z*4 + (row>>5))*32 + (row&31))*(size_t)M + m] = f2bf(v);
                }
    } else {
        float scale = role ? 1.f : QK_SCALE;
        #pragma unroll
        for (int a = 0; a < 2; ++a)
            #pragma unroll
            for (int c = 0; c < 2; ++c)
                #pragma unroll
                for (int r = 0; r < 4; ++r) {
                    int rl = wr + a*16 + quad*4 + r;
                    tb[rl*66 + wc + c*16 + l15] = acc[a][c][r] + bias[o0 + rl];
                }
        __syncthreads();
        u16* ohi = role ? kthi : qthi;
        u16* olo = role ? ktlo : qtlo;
        int n = t >> 2, rb = (t & 3)*16;
        #pragma unroll
        for (int g = 0; g < 2; ++g) {
            short8 hi, lo;
            #pragma unroll
            for (int j = 0; j < 8; ++j) {
                float v = tb[(rb + g*8 + j)*66 + n] * scale;
                u16 hb = f2bf(v);
                hi[j] = (short)hb;
                lo[j] = (short)f2bf(v - bf2f(hb));
            }
            int rowg = o0 + rb + g*8;
            size_t ob = ((size_t)(z*4 + (rowg >> 5))*nCols + n0 + n)*32 + (rowg & 31);
            *(short8*)&ohi[ob] = hi;
            *(short8*)&olo[ob] = lo;
        }
    }
}

// ---------------------------------------------------------------------------
// Attention v10: round-16 v8 body, pass-2 pcol reduce moved to DPP (VALU)
// and per-qp pcol buffers with plain stores (no LDS atomics).
// ---------------------------------------------------------------------------
__global__ __launch_bounds__(512, 4) void attn4_kernel(
    const u16* __restrict__ qthi, const u16* __restrict__ qtlo,
    const u16* __restrict__ kthi, const u16* __restrict__ ktlo,
    const u16* __restrict__ vthi, int M,
    u16* __restrict__ msghi, u16* __restrict__ msglo, float* __restrict__ p)
{
    __shared__ float pcolA[2048], pcolB[2048];
    __shared__ float obuf[96*66];        // mh-partial merge + msg pack (25.3 KB)
    __shared__ float redm[4][64], redl[4][64];
    __shared__ float rowM[64], rowIV[64];

    const int t = threadIdx.x;
    const int lane = t & 63, wave = t >> 6;
    const int l15 = lane & 15, quad = lane >> 4;
    const int qp = wave & 1, mh = wave >> 1;     // mh 0..3
    const int h = blockIdx.y, z = blockIdx.z;
    const int zh = z*4 + h;
    const int n0 = blockIdx.x * 64;

    for (int i = t; i < M; i += 512) { pcolA[i] = 0.f; pcolB[i] = 0.f; }

    short8 qBh[2], qBl[2];
    #pragma unroll
    for (int qt = 0; qt < 2; ++qt) {
        size_t qb = ((size_t)zh*NN + n0 + qp*32 + qt*16 + l15)*32 + quad*8;
        qBh[qt] = *(const short8*)&qthi[qb];
        qBl[qt] = *(const short8*)&qtlo[qb];
    }

    const int nch = M >> 7;
    const size_t kb0 = ((size_t)zh*M + mh*32 + l15)*32 + quad*8;
    const u16* kbh = kthi + kb0;
    const u16* kbl = ktlo + kb0;
    const u16* vb = vthi + ((size_t)zh*32 + l15)*M + mh*32 + quad*8;

    float rm[2] = {-1e30f, -1e30f}, rl[2] = {0.f, 0.f};

    // ---- pass 1: (m,l) from 3-term scores (fp32-grade, exp2 domain) ----
    for (int ch = 0; ch < nch; ++ch) {
        const int co = ch*128*32;
        #pragma unroll
        for (int mt = 0; mt < 2; ++mt) {
            short8 kh = *(const short8*)&kbh[co + mt*512];
            short8 kl = *(const short8*)&kbl[co + mt*512];
            __builtin_amdgcn_s_setprio(1);
            f32x4 av[2];
            #pragma unroll
            for (int qt = 0; qt < 2; ++qt) {
                f32x4 a = {0.f,0.f,0.f,0.f};
                a = __builtin_amdgcn_mfma_f32_16x16x32_bf16(kh, qBl[qt], a, 0,0,0);
                a = __builtin_amdgcn_mfma_f32_16x16x32_bf16(kl, qBh[qt], a, 0,0,0);
                a = __builtin_amdgcn_mfma_f32_16x16x32_bf16(kh, qBh[qt], a, 0,0,0);
                av[qt] = a;
            }
            __builtin_amdgcn_s_setprio(0);
            #pragma unroll
            for (int qt = 0; qt < 2; ++qt) {
                f32x4 a = av[qt];
                float bm = fmaxf(fmaxf(a[0],a[1]), fmaxf(a[2],a[3]));
                float bs = fexp2(a[0]-bm)+fexp2(a[1]-bm)+fexp2(a[2]-bm)+fexp2(a[3]-bm);
                if (bm > rm[qt]) { rl[qt] = rl[qt]*fexp2(rm[qt]-bm) + bs; rm[qt] = bm; }
                else rl[qt] += bs*fexp2(bm - rm[qt]);
            }
        }
    }

    #pragma unroll
    for (int qt = 0; qt < 2; ++qt) {
        #pragma unroll
        for (int off = 16; off <= 32; off <<= 1) {
            float om = __shfl_xor(rm[qt], off);
            float ol = __shfl_xor(rl[qt], off);
            float nm = fmaxf(rm[qt], om);
            rl[qt] = rl[qt]*fexp2(rm[qt]-nm) + ol*fexp2(om-nm);
            rm[qt] = nm;
        }
        if (quad == 0) {
            redm[mh][qp*32 + qt*16 + l15] = rm[qt];
            redl[mh][qp*32 + qt*16 + l15] = rl[qt];
        }
    }
    __syncthreads();
    if (t < 64) {
        float m = redm[0][t], l = redl[0][t];
        #pragma unroll
        for (int w2 = 1; w2 < 4; ++w2) {
            float om = redm[w2][t];
            float nm = fmaxf(m, om);
            l = l*fexp2(m - nm) + redl[w2][t]*fexp2(om - nm);
            m = nm;
        }
        rowM[t] = m;
        rowIV[t] = 1.f / l;
    }
    __syncthreads();
    float myRM[2], myRIV[2];
    #pragma unroll
    for (int qt = 0; qt < 2; ++qt) {
        myRM[qt]  = rowM[qp*32 + qt*16 + l15];
        myRIV[qt] = rowIV[qp*32 + qt*16 + l15];
    }

    // ---- pass 2: probs (3-term), pcol (DPP reduce), swapped PV ----
    f32x4 oa[2][2];
    #pragma unroll
    for (int qt = 0; qt < 2; ++qt)
        #pragma unroll
        for (int dt = 0; dt < 2; ++dt) oa[qt][dt] = (f32x4){0.f,0.f,0.f,0.f};

    const int aA = (l15 + 32*(quad & 1))*4;
    const int aB = aA + 64;
    const bool mtsel = (quad >= 2);
    float* pcolQ = qp ? pcolB : pcolA;

    for (int ch = 0; ch < nch; ++ch) {
        const int m0 = ch << 7;
        const int co = ch*128*32;

        float pr[2][2][4];
        #pragma unroll
        for (int mt = 0; mt < 2; ++mt) {
            short8 kh = *(const short8*)&kbh[co + mt*512];
            short8 kl = *(const short8*)&kbl[co + mt*512];
            __builtin_amdgcn_s_setprio(1);
            f32x4 av[2];
            #pragma unroll
            for (int qt = 0; qt < 2; ++qt) {
                f32x4 a = {0.f,0.f,0.f,0.f};
                a = __builtin_amdgcn_mfma_f32_16x16x32_bf16(kh, qBl[qt], a, 0,0,0);
                a = __builtin_amdgcn_mfma_f32_16x16x32_bf16(kl, qBh[qt], a, 0,0,0);
                a = __builtin_amdgcn_mfma_f32_16x16x32_bf16(kh, qBh[qt], a, 0,0,0);
                av[qt] = a;
            }
            __builtin_amdgcn_s_setprio(0);
            #pragma unroll
            for (int qt = 0; qt < 2; ++qt)
                #pragma unroll
                for (int r = 0; r < 4; ++r)
                    pr[qt][mt][r] = fexp2(av[qt][r] - myRM[qt]);
        }

        // pcol: 16-lane reduce on VALU via DPP row-rotate, plain store per qp
        #pragma unroll
        for (int mt = 0; mt < 2; ++mt)
            #pragma unroll
            for (int r = 0; r < 4; ++r) {
                float ps = pr[0][mt][r]*myRIV[0] + pr[1][mt][r]*myRIV[1];
                ps += ROR16F(ps, 8);
                ps += ROR16F(ps, 4);
                ps += ROR16F(ps, 2);
                ps += ROR16F(ps, 1);
                if (l15 == 0)
                    pcolQ[m0 + mh*32 + mt*16 + quad*4 + r] = ps;
            }

        short8 vA[2];
        #pragma unroll
        for (int dt = 0; dt < 2; ++dt)
            vA[dt] = *(const short8*)&vb[(size_t)dt*16*M + m0];

        #pragma unroll
        for (int qt = 0; qt < 2; ++qt) {
            unsigned pk00 = cvtpk_bf16(pr[qt][0][0], pr[qt][0][1]);
            unsigned pk01 = cvtpk_bf16(pr[qt][0][2], pr[qt][0][3]);
            unsigned pk10 = cvtpk_bf16(pr[qt][1][0], pr[qt][1][1]);
            unsigned pk11 = cvtpk_bf16(pr[qt][1][2], pr[qt][1][3]);
            unsigned a0 = (unsigned)__builtin_amdgcn_ds_bpermute(aA, (int)pk00);
            unsigned a1 = (unsigned)__builtin_amdgcn_ds_bpermute(aA, (int)pk01);
            unsigned a2 = (unsigned)__builtin_amdgcn_ds_bpermute(aA, (int)pk10);
            unsigned a3 = (unsigned)__builtin_amdgcn_ds_bpermute(aA, (int)pk11);
            unsigned b0 = (unsigned)__builtin_amdgcn_ds_bpermute(aB, (int)pk00);
            unsigned b1 = (unsigned)__builtin_amdgcn_ds_bpermute(aB, (int)pk01);
            unsigned b2 = (unsigned)__builtin_amdgcn_ds_bpermute(aB, (int)pk10);
            unsigned b3 = (unsigned)__builtin_amdgcn_ds_bpermute(aB, (int)pk11);
            union { unsigned u[4]; short8 s; } fb;
            fb.u[0] = mtsel ? a2 : a0;
            fb.u[1] = mtsel ? a3 : a1;
            fb.u[2] = mtsel ? b2 : b0;
            fb.u[3] = mtsel ? b3 : b1;
            __builtin_amdgcn_s_setprio(1);
            #pragma unroll
            for (int dt = 0; dt < 2; ++dt)
                oa[qt][dt] = __builtin_amdgcn_mfma_f32_16x16x32_bf16(vA[dt], fb.s, oa[qt][dt], 0,0,0);
            __builtin_amdgcn_s_setprio(0);
        }
    }

    if (mh > 0) {
        #pragma unroll
        for (int qt = 0; qt < 2; ++qt)
            #pragma unroll
            for (int dt = 0; dt < 2; ++dt)
                #pragma unroll
                for (int r = 0; r < 4; ++r) {
                    int q = qp*32 + qt*16 + l15;
                    int d = dt*16 + quad*4 + r;
                    obuf[((mh-1)*32 + d)*66 + q] = oa[qt][dt][r];
                }
    }
    __syncthreads();
    if (mh == 0) {
        #pragma unroll
        for (int qt = 0; qt < 2; ++qt)
            #pragma unroll
            for (int dt = 0; dt < 2; ++dt)
                #pragma unroll
                for (int r = 0; r < 4; ++r) {
                    int q = qp*32 + qt*16 + l15;
                    int d = dt*16 + quad*4 + r;
                    float v = oa[qt][dt][r];
                    #pragma unroll
                    for (int w2 = 0; w2 < 3; ++w2)
                        v += obuf[(w2*32 + d)*66 + q];
                    obuf[d*66 + q] = v * myRIV[qt];
                }
    }
    __syncthreads();
    {
        int tt = t & 255;
        int n = tt >> 2, i8 = (tt & 3)*8;
        short8 o8;
        if (t < 256) {
            #pragma unroll
            for (int j = 0; j < 8; ++j) o8[j] = (short)f2bf(obuf[(i8+j)*66 + n]);
            *(short8*)&msghi[((size_t)z*NN + n0 + n)*128 + h*32 + i8] = o8;
        } else {
            #pragma unroll
            for (int j = 0; j < 8; ++j) {
                float v = obuf[(i8+j)*66 + n];
                u16 hb = f2bf(v);
                o8[j] = (short)f2bf(v - bf2f(hb));
            }
            *(short8*)&msglo[((size_t)z*NN + n0 + n)*128 + h*32 + i8] = o8;
        }
    }
    for (int i = t; i < M; i += 512)
        atomicAdd(&p[(size_t)z*NN + i], (pcolA[i] + pcolB[i])*0.25f);
}

// ---------------------------------------------------------------------------
// W1: z = W1a x + W1b' msg + b1' -> TRANSPOSED zf_t [z][n][256] (fp32) via
// LDS transpose + instnorm stats atomics.
// ---------------------------------------------------------------------------
__global__ __launch_bounds__(256) void w1_kernel(
    const u16* __restrict__ W1h, const u16* __restrict__ W1l,
    const float* __restrict__ b1,
    const u16* __restrict__ xphi, const u16* __restrict__ xplo,
    const u16* __restrict__ m2hi, const u16* __restrict__ m2lo,
    float* __restrict__ zft, float* __restrict__ gsum, float* __restrict__ gsq)
{
    __shared__ u16 gsm[10240];
    u16* As0 = gsm;  u16* As1 = gsm + 2560;
    u16* Bs0 = gsm + 5120; u16* Bs1 = gsm + 7680;
    float* tb = (float*)gsm;                 // [64][66] after gcore

    const int z = blockIdx.z, o0 = blockIdx.y*64, n0 = blockIdx.x*64;
    const int t = threadIdx.x;
    const int lane = t & 63, w = t >> 6;
    const int l15 = lane & 15, quad = lane >> 4;
    const int wr = (w & 1)*32, wc = (w >> 1)*32;

    f32x4 acc[2][2];
    #pragma unroll
    for (int a = 0; a < 2; ++a)
        #pragma unroll
        for (int c = 0; c < 2; ++c) acc[a][c] = (f32x4){0.f,0.f,0.f,0.f};
    gcore(As0, As1, Bs0, Bs1, W1h, W1l, o0, 256,
          xphi, xplo, 128, m2hi, m2lo, 128, 128,
          (size_t)z*NN, n0, nullptr, t, acc);

    float ssum[2][4], ssq[2][4];
    #pragma unroll
    for (int a = 0; a < 2; ++a)
        #pragma unroll
        for (int r = 0; r < 4; ++r) { ssum[a][r] = 0.f; ssq[a][r] = 0.f; }
    #pragma unroll
    for (int a = 0; a < 2; ++a)
        #pragma unroll
        for (int c = 0; c < 2; ++c)
            #pragma unroll
            for (int r = 0; r < 4; ++r) {
                int rl = wr + a*16 + quad*4 + r;
                int cl = wc + c*16 + l15;
                float v = acc[a][c][r] + b1[o0 + rl];
                tb[rl*66 + cl] = v;
                ssum[a][r] += v;
                ssq[a][r] = fmaf(v, v, ssq[a][r]);
            }
    #pragma unroll
    for (int a = 0; a < 2; ++a)
        #pragma unroll
        for (int r = 0; r < 4; ++r) {
            float s = ssum[a][r], q2 = ssq[a][r];
            #pragma unroll
            for (int o = 1; o < 16; o <<= 1) {
                s  += __shfl_xor(s, o);
                q2 += __shfl_xor(q2, o);
            }
            if (l15 == 0) {
                int row = o0 + wr + a*16 + quad*4 + r;
                atomicAdd(&gsum[z*256 + row], s);
                atomicAdd(&gsq[z*256 + row], q2);
            }
        }
    __syncthreads();
    // transposed write: zf_t[(z*NN + n0+n)*256 + o0 + c]
    int n = t >> 2, rb = (t & 3)*16;
    #pragma unroll
    for (int g = 0; g < 2; ++g) {
        float4 v0, v1;
        v0.x = tb[(rb + g*8 + 0)*66 + n];
        v0.y = tb[(rb + g*8 + 1)*66 + n];
        v0.z = tb[(rb + g*8 + 2)*66 + n];
        v0.w = tb[(rb + g*8 + 3)*66 + n];
        v1.x = tb[(rb + g*8 + 4)*66 + n];
        v1.y = tb[(rb + g*8 + 5)*66 + n];
        v1.z = tb[(rb + g*8 + 6)*66 + n];
        v1.w = tb[(rb + g*8 + 7)*66 + n];
        float* dst = &zft[((size_t)z*NN + n0 + n)*256 + o0 + rb + g*8];
        *(float4*)dst = v0;
        *(float4*)(dst + 4) = v1;
    }
}

// ---------------------------------------------------------------------------
// W2: x += W2·relu(instnorm(z)) + b2 (fp32), instnorm inline from zf_t,
// and refresh x planes (unless last layer). hrepack fused away.
// ---------------------------------------------------------------------------
__global__ __launch_bounds__(256) void w2_kernel(
    const u16* __restrict__ W2h, const u16* __restrict__ W2l,
    const float* __restrict__ b2,
    const float* __restrict__ zft, const float* __restrict__ gsum,
    const float* __restrict__ gsq,
    float* __restrict__ out, u16* __restrict__ xphi, u16* __restrict__ xplo,
    int writeplanes)
{
    __shared__ u16 gsm[10240];
    __shared__ float meanL[256], ivL[256];
    u16* As0 = gsm;  u16* As1 = gsm + 2560;
    u16* Bs0 = gsm + 5120; u16* Bs1 = gsm + 7680;
    float* tb = (float*)gsm;

    const int z = blockIdx.z, o0 = blockIdx.y*64, n0 = blockIdx.x*64;
    const int t = threadIdx.x;
    const int lane = t & 63, w = t >> 6;
    const int l15 = lane & 15, quad = lane >> 4;
    const int wr = (w & 1)*32, wc = (w >> 1)*32;

    {
        float mean = gsum[z*256 + t] * (1.f/NN);
        float var  = gsq[z*256 + t] * (1.f/NN) - mean*mean;
        meanL[t] = mean;
        ivL[t] = rsqrtf(var + IN_EPS);
    }
    __syncthreads();

    f32x4 acc[2][2];
    #pragma unroll
    for (int a = 0; a < 2; ++a)
        #pragma unroll
        for (int c = 0; c < 2; ++c) acc[a][c] = (f32x4){0.f,0.f,0.f,0.f};
    gcore_w2(As0, As1, Bs0, Bs1, W2h, W2l, o0,
             zft, meanL, ivL, (size_t)z*NN, n0, t, acc);

    #pragma unroll
    for (int a = 0; a < 2; ++a)
        #pragma unroll
        for (int c = 0; c < 2; ++c)
            #pragma unroll
            for (int r = 0; r < 4; ++r) {
                int rl = wr + a*16 + quad*4 + r;
                int rowg = o0 + rl;
                int n = n0 + wc + c*16 + l15;
                size_t oi = ((size_t)z*128 + rowg)*NN + n;
                float v = acc[a][c][r] + b2[rowg] + out[oi];
                out[oi] = v;
                tb[rl*66 + wc + c*16 + l15] = v;
            }
    __syncthreads();
    if (writeplanes) {
        int n = t >> 2, rb = (t & 3)*16;
        #pragma unroll
        for (int g = 0; g < 2; ++g) {
            short8 hi, lo;
            #pragma unroll
            for (int j = 0; j < 8; ++j) {
                float v = tb[(rb + g*8 + j)*66 + n];
                u16 hb = f2bf(v);
                hi[j] = (short)hb;
                lo[j] = (short)f2bf(v - bf2f(hb));
            }
            size_t ob = ((size_t)z*NN + n0 + n)*128 + o0 + rb + g*8;
            *(short8*)&xphi[ob] = hi;
            *(short8*)&xplo[ob] = lo;
        }
    }
}

// ---------------------------------------------------------------------------
__global__ __launch_bounds__(256) void rank_kernel(
    const float* __restrict__ p, int* __restrict__ rank, int M)
{
    int zz = blockIdx.y;
    __shared__ float pv[2048];
    for (int i = threadIdx.x; i < M; i += 256) pv[i] = p[(size_t)zz*NN + i];
    __syncthreads();
    int i = blockIdx.x * 256 + threadIdx.x;
    if (i < M) {
        float pi = pv[i];
        int r = 0;
        for (int j = 0; j < M; ++j) {
            float pj = pv[j];
            r += (pj > pi) ? 1 : ((pj == pi && j < i) ? 1 : 0);
        }
        rank[zz*NN + i] = r;
    }
}

__global__ __launch_bounds__(256) void select_kernel(
    const int* __restrict__ rank, int* __restrict__ idx0, int* __restrict__ idx1,
    int M, int k, int cross)
{
    int z = blockIdx.x;
    int st = z >> 1, b = z & 1;
    int ts = cross ? 1 - st : st;
    int* idx = (ts ? idx1 : idx0) + b * NN;
    const int* rk = rank + z * NN;
    __shared__ int sel[2048], idv[2048], sa[2048], sb[2048];
    int t = threadIdx.x;
    for (int i = t; i < M; i += 256) {
        int s = rk[i] < k ? 1 : 0;
        sel[i] = s;
        sa[i] = s;
        idv[i] = idx[i];
    }
    __syncthreads();
    int* src = sa; int* dst = sb;
    for (int off = 1; off < M; off <<= 1) {
        for (int i = t; i < M; i += 256)
            dst[i] = src[i] + (i >= off ? src[i - off] : 0);
        __syncthreads();
        int* tmp = src; src = dst; dst = tmp;
    }
    for (int i = t; i < M; i += 256)
        if (sel[i]) idx[src[i] - 1] = idv[i];
}

// ---------------------------------------------------------------------------
extern "C" void kernel_launch(void* const* d_in, const int* in_sizes, int n_in,
                              void* d_out, int out_size, void* d_ws, size_t ws_size,
                              hipStream_t stream)
{
    const float* x0in = (const float*)d_in[0];
    const float* x1in = (const float*)d_in[1];
    const float* Wq = (const float*)d_in[2];
    const float* bq = (const float*)d_in[3];
    const float* Wk = (const float*)d_in[4];
    const float* bk = (const float*)d_in[5];
    const float* Wv = (const float*)d_in[6];
    const float* bv = (const float*)d_in[7];
    const float* Wm = (const float*)d_in[8];
    const float* bm = (const float*)d_in[9];
    const float* W1 = (const float*)d_in[10];
    const float* b1 = (const float*)d_in[11];
    const float* W2 = (const float*)d_in[12];
    const float* b2 = (const float*)d_in[13];

    float* out = (float*)d_out;
    float* ws  = (float*)d_ws;

    const size_t U = 1048576;
    u16* ub   = (u16*)ws;
    u16* xphi = ub;            u16* xplo = ub + U;
    u16* qthi = ub + 2*U;      u16* qtlo = ub + 3*U;
    u16* kthi = ub + 4*U;      u16* ktlo = ub + 5*U;
    u16* vthi = ub + 6*U;
    u16* msghi = ub + 7*U;     u16* msglo = ub + 8*U;
    u16* whi  = ub + 15*U;     u16* wlo = whi + 655360;
    float* zft = (float*)(ub + 2*U);                       // aliases qt/kt (8 MB)
    float* ft = (float*)(wlo + 655360);
    float* bqp = ft;           float* bkp = ft + 512;      float* bvp = ft + 1024;
    float* gsum = ft + 1536;   float* gsq = ft + 2560;
    float* p = ft + 3584;                                  // [4][NN]
    int* idx0 = (int*)(p + 4*NN);
    int* idx1 = idx0 + NB*NN;
    int* rankb = idx1 + NB*NN;
    float* b1p = (float*)(rankb + 4*NN);                   // [4][256]

    init_kernel<<<BDN/4/256, 256, 0, stream>>>(x0in, x1in, out, idx0, idx1);
    wrepack2_kernel<<<2570, 256, 0, stream>>>(Wq, Wk, Wv, Wm, W1, W2, bq, bk, bv,
                                              bm, b1, whi, wlo, bqp, bkp, bvp, b1p);
    repack_xh_kernel<<<dim3(32, 16), 256, 0, stream>>>(out, xphi, xplo);

    const int Ms[4] = {2048, 1024, 512, 256};
    for (int l = 0; l < 4; ++l) {
        int M = Ms[l];
        int k_new = (M/2 < 128) ? 128 : M/2;
        int cross = l & 1;
        size_t lw = (size_t)l * 163840;
        const u16* Wlh = whi + lw;  const u16* Wll = wlo + lw;

        qkv_kernel<<<dim3(64 + 4*(M/64), 1, 4), 256, 0, stream>>>(
            Wlh, Wll, bqp + l*128, bkp + l*128, bvp + l*128,
            xphi, xplo, idx0, idx1, cross, M,
            qthi, qtlo, kthi, ktlo, vthi, p, gsum, gsq);

        attn4_kernel<<<dim3(32, NH, 4), 512, 0, stream>>>(
            qthi, qtlo, kthi, ktlo, vthi, M, msghi, msglo, p);

        w1_kernel<<<dim3(32, 4, 4), 256, 0, stream>>>(
            Wlh + 65536, Wll + 65536, b1p + l*256,
            xphi, xplo, msghi, msglo, zft, gsum, gsq);

        w2_kernel<<<dim3(32, 2, 4), 256, 0, stream>>>(
            Wlh + 131072, Wll + 131072, b2 + l*128,
            zft, gsum, gsq, out, xphi, xplo, (l < 3) ? 1 : 0);

        rank_kernel<<<dim3((M+255)/256, 4), 256, 0, stream>>>(p, rankb, M);
        select_kernel<<<4, 256, 0, stream>>>(rankb, idx0, idx1, M, k_new, cross);
    }
}